// Round 6
// baseline (194.418 us; speedup 1.0000x reference)
//
#include <hip/hip_runtime.h>
#include <math.h>

#define DIM   2048
#define NEXP  64
#define TOPK  8
#define BM    32
#define NT    256
#define KT    32           // K tiles of BK=64
#define NBLK  512          // M / BM

typedef __attribute__((ext_vector_type(8)))  short bf16x8;
typedef __attribute__((ext_vector_type(16))) float f32x16;

#define MFMA(A, B, C) __builtin_amdgcn_mfma_f32_32x32x16_bf16(A, B, C, 0, 0, 0)
#define AS_BF(v) (*(const bf16x8*)&(v))

__device__ inline unsigned int bfpack(float a, float b) {
    unsigned int ua = __float_as_uint(a), ub = __float_as_uint(b);
    unsigned int lo = (ua + 0x7FFFu + ((ua >> 16) & 1u)) >> 16;
    unsigned int hi = (ub + 0x7FFFu + ((ub >> 16) & 1u)) & 0xFFFF0000u;
    return hi | lo;
}
__device__ inline void split2pair(float a, float b, unsigned int& h, unsigned int& m) {
    h = bfpack(a, b);
    float ra = a - __uint_as_float(h << 16);
    float rb = b - __uint_as_float(h & 0xFFFF0000u);
    m = bfpack(ra, rb);
}

// w[e][k] f32 -> per-K64-tile fragment-ordered 2-term bf16:
// byte = kt*16384 + (ks*2+kh)*2048 + term*1024 + e*16
__global__ __launch_bounds__(256) void prep_kernel(const float* __restrict__ w,
                                                   unsigned int* __restrict__ wpack) {
    const int u = blockIdx.x * 256 + threadIdx.x;   // 0..16383
    const int e = u >> 8, k8 = u & 255;
    const float4 v0 = *(const float4*)(w + (size_t)e * DIM + k8 * 8);
    const float4 v1 = *(const float4*)(w + (size_t)e * DIM + k8 * 8 + 4);
    unsigned int h[4], m[4];
    split2pair(v0.x, v0.y, h[0], m[0]);
    split2pair(v0.z, v0.w, h[1], m[1]);
    split2pair(v1.x, v1.y, h[2], m[2]);
    split2pair(v1.z, v1.w, h[3], m[3]);
    const int kt = k8 >> 3, r = k8 & 7, ks = r >> 1, kh = r & 1;
    char* base = (char*)wpack + (size_t)kt * 16384 + (ks * 2 + kh) * 2048 + e * 16;
    *(uint4*)(base)        = (uint4){h[0], h[1], h[2], h[3]};
    *(uint4*)(base + 1024) = (uint4){m[0], m[1], m[2], m[3]};
}

// pure-read BW probe over x (also pre-warms L3); no global writes
__global__ __launch_bounds__(256) void probe_kernel(const float* __restrict__ x) {
    const float4* x4 = (const float4*)x;
    const size_t i = (size_t)blockIdx.x * 256 + threadIdx.x;   // grid 2048*256
    float s = 0.f;
    #pragma unroll
    for (int j = 0; j < 16; ++j) {
        float4 v = x4[i + (size_t)j * 524288];
        s += v.x + v.y + v.z + v.w;
    }
    asm volatile("" :: "v"(s));   // keep live, rule #17
}

__global__ __launch_bounds__(NT, 2) void router_kernel(
    const float* __restrict__ x,
    const unsigned int* __restrict__ wpack,
    const float* __restrict__ bias,
    float* __restrict__ out,     // [M*8] scores | [M*8] idx(f32) | [64] counts(f32)
    int* __restrict__ histws,    // [NBLK][64]
    int M)
{
    __shared__ __align__(16) char smem[24576 + 256];   // xs 8K | ws 16K ; lg aliases; hist at end
    char* smemc = smem;
    int* hist = (int*)(smem + 24576);

    const int tid = threadIdx.x;
    const int bid = blockIdx.x;
    const int swz = (bid & 7) * (NBLK / 8) + (bid >> 3);   // bijective XCD swizzle
    const int row0 = swz * BM;
    if (tid < NEXP) hist[tid] = 0;

    // ---- staging addresses: LDS linear, global pre-swizzled (rule #21) ----
    // x: granule G = p*256 + tid ; r = G>>4, gl = G&15, gg = gl ^ (r&15)
    const int r0 = tid >> 4, gl = tid & 15;
    const int gg = gl ^ (r0 & 15);
    const float* xg0 = x + (size_t)(row0 + r0) * DIM + gg * 4;        // p=0 rows 0..15
    const float* xg1 = xg0 + (size_t)16 * DIM;                        // p=1 rows 16..31
    const char*  wg  = (const char*)wpack + tid * 16;
    char* xsp = smemc + tid * 16;           // xs linear
    char* wsp = smemc + 8192 + tid * 16;    // ws linear

    // ---- compute roles: 4 waves = (expert half eq) x (split-K s) ----
    const int wv   = tid >> 6;
    const int lane = tid & 63;
    const int lr   = lane & 31;
    const int kh   = lane >> 5;
    const int eq   = wv & 1;
    const int s    = wv >> 1;
    const int xr   = lr & 15;
    const int lroff = lr * 256;
    const int jj0 = 4 * s + kh;          // ks = 2s
    const int jj1 = jj0 + 2;             // ks = 2s+1
    const int ax0  = ((2 * jj0)     ^ xr) << 4;
    const int ax0b = ((2 * jj0 + 1) ^ xr) << 4;
    const int ax1  = ((2 * jj1)     ^ xr) << 4;
    const int ax1b = ((2 * jj1 + 1) ^ xr) << 4;
    const int wo0 = 8192 + jj0 * 2048 + (eq * 32 + lr) * 16;
    const int wo1 = 8192 + jj1 * 2048 + (eq * 32 + lr) * 16;

    f32x16 acc = {};

    float4 pxA[2], pxB[2];
    uint4  pw0[2], pw1[2], pw2[2], pw3[2];

#define LOAD(sl, kt)                                                   \
    do {                                                               \
        pxA[sl] = *(const float4*)(xg0 + (kt) * 64);                   \
        pxB[sl] = *(const float4*)(xg1 + (kt) * 64);                   \
        const char* wt = wg + (size_t)(kt) * 16384;                    \
        pw0[sl] = *(const uint4*)(wt);                                 \
        pw1[sl] = *(const uint4*)(wt + 4096);                          \
        pw2[sl] = *(const uint4*)(wt + 8192);                          \
        pw3[sl] = *(const uint4*)(wt + 12288);                         \
    } while (0)

#define DOSPLIT(vlo, vhi, hv, mv)                                      \
    do {                                                               \
        unsigned int h_[4], m_[4];                                     \
        split2pair((vlo).x, (vlo).y, h_[0], m_[0]);                    \
        split2pair((vlo).z, (vlo).w, h_[1], m_[1]);                    \
        split2pair((vhi).x, (vhi).y, h_[2], m_[2]);                    \
        split2pair((vhi).z, (vhi).w, h_[3], m_[3]);                    \
        hv = (uint4){h_[0], h_[1], h_[2], h_[3]};                      \
        mv = (uint4){m_[0], m_[1], m_[2], m_[3]};                      \
    } while (0)

#define STEP(sl, kt)                                                   \
    do {                                                               \
        asm volatile("s_barrier" ::: "memory");                        \
        *(float4*)(xsp)        = pxA[sl];                              \
        *(float4*)(xsp + 4096) = pxB[sl];                              \
        *(uint4*)(wsp)          = pw0[sl];                             \
        *(uint4*)(wsp + 4096)   = pw1[sl];                             \
        *(uint4*)(wsp + 8192)   = pw2[sl];                             \
        *(uint4*)(wsp + 12288)  = pw3[sl];                             \
        if ((kt) + 2 < KT) LOAD(sl, (kt) + 2);                         \
        asm volatile("s_waitcnt lgkmcnt(0)" ::: "memory");             \
        __builtin_amdgcn_sched_barrier(0);                             \
        asm volatile("s_barrier" ::: "memory");                        \
        {                                                              \
            float4 alo0 = *(const float4*)(smemc + lroff + ax0);       \
            float4 ahi0 = *(const float4*)(smemc + lroff + ax0b);      \
            float4 alo1 = *(const float4*)(smemc + lroff + ax1);       \
            float4 ahi1 = *(const float4*)(smemc + lroff + ax1b);      \
            uint4 b0h = *(const uint4*)(smemc + wo0);                  \
            uint4 b0m = *(const uint4*)(smemc + wo0 + 1024);           \
            uint4 b1h = *(const uint4*)(smemc + wo1);                  \
            uint4 b1m = *(const uint4*)(smemc + wo1 + 1024);           \
            uint4 a0h, a0m, a1h, a1m;                                  \
            DOSPLIT(alo0, ahi0, a0h, a0m);                             \
            DOSPLIT(alo1, ahi1, a1h, a1m);                             \
            acc = MFMA(AS_BF(a0h), AS_BF(b0h), acc);                   \
            acc = MFMA(AS_BF(a0m), AS_BF(b0h), acc);                   \
            acc = MFMA(AS_BF(a0h), AS_BF(b0m), acc);                   \
            acc = MFMA(AS_BF(a1h), AS_BF(b1h), acc);                   \
            acc = MFMA(AS_BF(a1m), AS_BF(b1h), acc);                   \
            acc = MFMA(AS_BF(a1h), AS_BF(b1m), acc);                   \
        }                                                              \
    } while (0)

    LOAD(0, 0);
    LOAD(1, 1);
    for (int kt = 0; kt < KT; kt += 2) {
        STEP(0, kt);
        STEP(1, kt + 1);
    }
#undef STEP
#undef DOSPLIT
#undef LOAD

    __syncthreads();

    // ---- split-K reduce + bias into lg[32][66] (aliases xs/ws) ----
    float* lg = (float*)smemc;
    const float biasv = bias[eq * 32 + lr];
    if (s == 0) {
        #pragma unroll
        for (int r = 0; r < 16; ++r) {
            const int rr = (r & 3) + 8 * (r >> 2) + 4 * kh;   // verified C-layout
            lg[rr * 66 + eq * 32 + lr] = acc[r];
        }
    }
    __syncthreads();
    if (s == 1) {
        #pragma unroll
        for (int r = 0; r < 16; ++r) {
            const int rr = (r & 3) + 8 * (r >> 2) + 4 * kh;
            const int idx = rr * 66 + eq * 32 + lr;
            lg[idx] = lg[idx] + acc[r] + biasv;
        }
    }
    __syncthreads();

    // ---- top-k + softmax + histogram (verified epilogue) ----
    float* out_scores = out;
    float* out_idx    = out + (size_t)M * TOPK;

    for (int r8 = 0; r8 < 8; ++r8) {
        const int row = wv * 8 + r8;
        float vm = lg[row * 66 + lane];
        float vals[TOPK];
        int   ids[TOPK];
        #pragma unroll
        for (int k = 0; k < TOPK; ++k) {
            float mv = vm;
            int   mi = lane;
            #pragma unroll
            for (int off = 32; off > 0; off >>= 1) {
                float ov = __shfl_xor(mv, off);
                int   oi = __shfl_xor(mi, off);
                if (ov > mv || (ov == mv && oi < mi)) { mv = ov; mi = oi; }
            }
            vals[k] = mv; ids[k] = mi;
            if (lane == mi) { vm = -INFINITY; atomicAdd(&hist[mi], 1); }
        }
        if (lane == 0) {
            const float m = vals[0];
            float e[TOPK];
            float ssum = 0.f;
            #pragma unroll
            for (int k = 0; k < TOPK; ++k) { e[k] = expf(vals[k] - m); ssum += e[k]; }
            const float inv = 1.0f / ssum;
            const size_t base = (size_t)(row0 + row) * TOPK;
            #pragma unroll
            for (int k = 0; k < TOPK; ++k) {
                out_scores[base + k] = e[k] * inv;
                out_idx[base + k]    = (float)ids[k];
            }
        }
    }

    __syncthreads();
    if (tid < NEXP) histws[bid * NEXP + tid] = hist[tid];
}

__global__ __launch_bounds__(512) void reduce_kernel(const int* __restrict__ histws,
                                                     float* __restrict__ counts) {
    __shared__ int part[8][NEXP];
    const int t = threadIdx.x;
    const int e = t & 63, c = t >> 6;
    int s = 0;
    for (int b = c; b < NBLK; b += 8) s += histws[b * NEXP + e];
    part[c][e] = s;
    __syncthreads();
    if (t < NEXP) {
        int tot = 0;
        #pragma unroll
        for (int i = 0; i < 8; ++i) tot += part[i][t];
        counts[t] = (float)tot;
    }
}

extern "C" void kernel_launch(void* const* d_in, const int* in_sizes, int n_in,
                              void* d_out, int out_size, void* d_ws, size_t ws_size,
                              hipStream_t stream) {
    const float* x    = (const float*)d_in[0];
    const float* w    = (const float*)d_in[1];
    const float* bias = (const float*)d_in[2];
    float* out = (float*)d_out;
    const int M = in_sizes[0] / DIM;   // 16384 rows

    unsigned int* wpack = (unsigned int*)d_ws;                      // 512 KB
    int* histws = (int*)((char*)d_ws + (size_t)NEXP * DIM * 4);     // 128 KB
    float* out_counts = out + (size_t)2 * M * TOPK;

    probe_kernel<<<2048, 256, 0, stream>>>(x);
    prep_kernel<<<64, 256, 0, stream>>>(w, wpack);
    router_kernel<<<NBLK, NT, 0, stream>>>(x, wpack, bias, out, histws, M);
    reduce_kernel<<<1, 512, 0, stream>>>(histws, out_counts);
}

// Round 7
// 106.583 us; speedup vs baseline: 1.8241x; 1.8241x over previous
//
#include <hip/hip_runtime.h>
#include <math.h>

#define DIM   2048
#define NEXP  64
#define TOPK  8
#define BM    32
#define NT    256
#define KT    32           // K64 tiles
#define NBLK  512          // M / BM

typedef __attribute__((ext_vector_type(8)))  short bf16x8;
typedef __attribute__((ext_vector_type(16))) float f32x16;

#define MFMA(A, B, C) __builtin_amdgcn_mfma_f32_32x32x16_bf16(A, B, C, 0, 0, 0)
#define AS_BF(v) (*(const bf16x8*)&(v))

__device__ inline unsigned int bfpack(float a, float b) {
    unsigned int ua = __float_as_uint(a), ub = __float_as_uint(b);
    unsigned int lo = (ua + 0x7FFFu + ((ua >> 16) & 1u)) >> 16;
    unsigned int hi = (ub + 0x7FFFu + ((ub >> 16) & 1u)) & 0xFFFF0000u;
    return hi | lo;
}
__device__ inline void split2pair(float a, float b, unsigned int& h, unsigned int& m) {
    h = bfpack(a, b);
    float ra = a - __uint_as_float(h << 16);
    float rb = b - __uint_as_float(h & 0xFFFF0000u);
    m = bfpack(ra, rb);
}

// w[e][k] f32 -> B-fragment order, 2-term bf16:
// byte = kt*16384 + j*4096 + term*2048 + kh*1024 + eq*512 + (e&31)*16
//   where k = kt*64 + j*16 + kh*8 + (0..7), eq = e>>5
__global__ __launch_bounds__(256) void prep_kernel(const float* __restrict__ w,
                                                   unsigned int* __restrict__ wpack) {
    const int u = blockIdx.x * 256 + threadIdx.x;   // 0..16383
    const int e = u >> 8, k8 = u & 255;
    const float4 v0 = *(const float4*)(w + (size_t)e * DIM + k8 * 8);
    const float4 v1 = *(const float4*)(w + (size_t)e * DIM + k8 * 8 + 4);
    unsigned int h[4], m[4];
    split2pair(v0.x, v0.y, h[0], m[0]);
    split2pair(v0.z, v0.w, h[1], m[1]);
    split2pair(v1.x, v1.y, h[2], m[2]);
    split2pair(v1.z, v1.w, h[3], m[3]);
    const int kt = k8 >> 3, j = (k8 & 7) >> 1, kh = k8 & 1;
    const int eq = e >> 5, e5 = e & 31;
    char* base = (char*)wpack + (size_t)kt * 16384 + j * 4096 + kh * 1024 + eq * 512 + e5 * 16;
    *(uint4*)(base)        = (uint4){h[0], h[1], h[2], h[3]};
    *(uint4*)(base + 2048) = (uint4){m[0], m[1], m[2], m[3]};
}

__global__ __launch_bounds__(NT, 2) void router_kernel(
    const float* __restrict__ x,
    const unsigned int* __restrict__ wpack,
    const float* __restrict__ bias,
    float* __restrict__ out,     // [M*8] scores | [M*8] idx(f32) | [64] counts(f32)
    int* __restrict__ histws,    // [NBLK][64]
    int M)
{
    __shared__ __align__(16) char xs[2][8192];
    __shared__ int hist[NEXP];

    const int tid = threadIdx.x;
    const int bid = blockIdx.x;
    const int swz = (bid & 7) * (NBLK / 8) + (bid >> 3);   // bijective XCD swizzle
    const int row0 = swz * BM;
    if (tid < NEXP) hist[tid] = 0;

    // ---- stager: thread -> 2 granules (rows sr / sr+16), global linear, LDS XOR-swizzled
    const int sr = tid >> 4, sc = tid & 15;
    const float* xg0 = x + (size_t)(row0 + sr) * DIM + sc * 4;
    const float* xg1 = xg0 + (size_t)16 * DIM;
    const int o0 = sr * 256 + ((sc ^ (sr & 7)) << 4);      // o1 = o0 + 4096

    // ---- compute roles: 4 waves = (expert-half eq) x (split-K s)
    const int wv = tid >> 6, lane = tid & 63;
    const int eq = wv & 1, s = wv >> 1;
    const int lr = lane & 31, kh = lane >> 5;
    const int rsw = lr & 7;
    const int c00 = (2 * s + 0) * 4 + kh * 2;
    const int c10 = (2 * s + 1) * 4 + kh * 2;
    const int ra00 = lr * 256 + (((c00 + 0) ^ rsw) << 4);
    const int ra01 = lr * 256 + (((c00 + 1) ^ rsw) << 4);
    const int ra10 = lr * 256 + (((c10 + 0) ^ rsw) << 4);
    const int ra11 = lr * 256 + (((c10 + 1) ^ rsw) << 4);
    const char* wgb = (const char*)wpack + (2 * s) * 4096 + kh * 1024 + eq * 512 + lr * 16;

    f32x16 acc = {};
    float4 xp0[4], xp1[4];
    uint4 wh0[2], wm0[2], wh1[2], wm1[2];

#define XLOAD(sl, kt) do { xp0[sl] = *(const float4*)(xg0 + (kt) * 64); \
                           xp1[sl] = *(const float4*)(xg1 + (kt) * 64); } while (0)
#define WLOAD(sl, kt) do { const char* wt_ = wgb + (size_t)(kt) * 16384; \
                           wh0[sl] = *(const uint4*)(wt_); \
                           wm0[sl] = *(const uint4*)(wt_ + 2048); \
                           wh1[sl] = *(const uint4*)(wt_ + 4096); \
                           wm1[sl] = *(const uint4*)(wt_ + 6144); } while (0)
#define XWRITE(sl, par) do { char* b_ = &xs[par][0]; \
                             *(float4*)(b_ + o0)        = xp0[sl]; \
                             *(float4*)(b_ + 4096 + o0) = xp1[sl]; } while (0)
#define DOSPLIT(vlo, vhi, hv, mv) do { \
        unsigned int h_[4], m_[4]; \
        split2pair((vlo).x, (vlo).y, h_[0], m_[0]); \
        split2pair((vlo).z, (vlo).w, h_[1], m_[1]); \
        split2pair((vhi).x, (vhi).y, h_[2], m_[2]); \
        split2pair((vhi).z, (vhi).w, h_[3], m_[3]); \
        hv = (uint4){h_[0], h_[1], h_[2], h_[3]}; \
        mv = (uint4){m_[0], m_[1], m_[2], m_[3]}; \
    } while (0)
#define COMPUTE(par, ws) do { \
        const char* buf_ = &xs[par][0]; \
        float4 a0_ = *(const float4*)(buf_ + ra00); \
        float4 a1_ = *(const float4*)(buf_ + ra01); \
        float4 a2_ = *(const float4*)(buf_ + ra10); \
        float4 a3_ = *(const float4*)(buf_ + ra11); \
        uint4 ah0_, am0_, ah1_, am1_; \
        DOSPLIT(a0_, a1_, ah0_, am0_); \
        DOSPLIT(a2_, a3_, ah1_, am1_); \
        acc = MFMA(AS_BF(ah0_), AS_BF(wh0[ws]), acc); \
        acc = MFMA(AS_BF(am0_), AS_BF(wh0[ws]), acc); \
        acc = MFMA(AS_BF(ah0_), AS_BF(wm0[ws]), acc); \
        acc = MFMA(AS_BF(ah1_), AS_BF(wh1[ws]), acc); \
        acc = MFMA(AS_BF(am1_), AS_BF(wh1[ws]), acc); \
        acc = MFMA(AS_BF(ah1_), AS_BF(wm1[ws]), acc); \
    } while (0)

    // prologue: 4 x-tiles + 2 w-tiles in flight; tile 0 into LDS[0]
    XLOAD(0, 0); XLOAD(1, 1); XLOAD(2, 2); XLOAD(3, 3);
    WLOAD(0, 0); WLOAD(1, 1);
    XWRITE(0, 0);
    asm volatile("s_waitcnt lgkmcnt(0)" ::: "memory");
    __builtin_amdgcn_s_barrier();

    // one barrier per tile; no vmcnt drains (counted waits via reg deps)
    #pragma unroll
    for (int t = 0; t < KT; ++t) {
        COMPUTE(t & 1, t & 1);
        if (t + 1 < KT) XWRITE((t + 1) & 3, (t + 1) & 1);
        if (t + 4 < KT) XLOAD(t & 3, t + 4);
        if (t + 2 < KT) WLOAD(t & 1, t + 2);
        asm volatile("s_waitcnt lgkmcnt(0)" ::: "memory");
        __builtin_amdgcn_s_barrier();
    }
#undef COMPUTE
#undef DOSPLIT
#undef XWRITE
#undef WLOAD
#undef XLOAD

    __syncthreads();

    // ---- split-K reduce + bias into lg[32][66] (aliases xs)
    float* lg = (float*)&xs[0][0];
    const float biasv = bias[eq * 32 + lr];
    if (s == 0) {
        #pragma unroll
        for (int r = 0; r < 16; ++r) {
            const int rr = (r & 3) + 8 * (r >> 2) + 4 * kh;   // verified C-layout
            lg[rr * 66 + eq * 32 + lr] = acc[r];
        }
    }
    __syncthreads();
    if (s == 1) {
        #pragma unroll
        for (int r = 0; r < 16; ++r) {
            const int rr = (r & 3) + 8 * (r >> 2) + 4 * kh;
            const int idx = rr * 66 + eq * 32 + lr;
            lg[idx] = lg[idx] + acc[r] + biasv;
        }
    }
    __syncthreads();

    // ---- top-k + softmax + histogram (verified epilogue); wave wv: rows wv*8..+8
    float* out_scores = out;
    float* out_idx    = out + (size_t)M * TOPK;

    for (int r8 = 0; r8 < 8; ++r8) {
        const int row = wv * 8 + r8;
        float vm = lg[row * 66 + lane];
        float vals[TOPK];
        int   ids[TOPK];
        #pragma unroll
        for (int k = 0; k < TOPK; ++k) {
            float mv = vm;
            int   mi = lane;
            #pragma unroll
            for (int off = 32; off > 0; off >>= 1) {
                float ov = __shfl_xor(mv, off);
                int   oi = __shfl_xor(mi, off);
                if (ov > mv || (ov == mv && oi < mi)) { mv = ov; mi = oi; }
            }
            vals[k] = mv; ids[k] = mi;
            if (lane == mi) { vm = -INFINITY; atomicAdd(&hist[mi], 1); }
        }
        if (lane == 0) {
            const float m = vals[0];
            float e[TOPK];
            float ssum = 0.f;
            #pragma unroll
            for (int k = 0; k < TOPK; ++k) { e[k] = expf(vals[k] - m); ssum += e[k]; }
            const float inv = 1.0f / ssum;
            const size_t base = (size_t)(row0 + row) * TOPK;
            #pragma unroll
            for (int k = 0; k < TOPK; ++k) {
                out_scores[base + k] = e[k] * inv;
                out_idx[base + k]    = (float)ids[k];
            }
        }
    }

    __syncthreads();
    if (tid < NEXP) histws[bid * NEXP + tid] = hist[tid];
}

__global__ __launch_bounds__(512) void reduce_kernel(const int* __restrict__ histws,
                                                     float* __restrict__ counts) {
    __shared__ int part[8][NEXP];
    const int t = threadIdx.x;
    const int e = t & 63, c = t >> 6;
    int sm = 0;
    for (int b = c; b < NBLK; b += 8) sm += histws[b * NEXP + e];
    part[c][e] = sm;
    __syncthreads();
    if (t < NEXP) {
        int tot = 0;
        #pragma unroll
        for (int i = 0; i < 8; ++i) tot += part[i][t];
        counts[t] = (float)tot;
    }
}

extern "C" void kernel_launch(void* const* d_in, const int* in_sizes, int n_in,
                              void* d_out, int out_size, void* d_ws, size_t ws_size,
                              hipStream_t stream) {
    const float* x    = (const float*)d_in[0];
    const float* w    = (const float*)d_in[1];
    const float* bias = (const float*)d_in[2];
    float* out = (float*)d_out;
    const int M = in_sizes[0] / DIM;   // 16384 rows

    unsigned int* wpack = (unsigned int*)d_ws;                      // 512 KB
    int* histws = (int*)((char*)d_ws + (size_t)NEXP * DIM * 4);     // 128 KB
    float* out_counts = out + (size_t)2 * M * TOPK;

    prep_kernel<<<64, 256, 0, stream>>>(w, wpack);
    router_kernel<<<NBLK, NT, 0, stream>>>(x, wpack, bias, out, histws, M);
    reduce_kernel<<<1, 512, 0, stream>>>(histws, out_counts);
}

// Round 8
// 86.000 us; speedup vs baseline: 2.2607x; 1.2393x over previous
//
#include <hip/hip_runtime.h>
#include <math.h>

#define DIM   2048
#define NEXP  64
#define TOPK  8
#define BM    32
#define NT    256
#define KT    32           // K64 tiles
#define NBLK  512          // M / BM

typedef __attribute__((ext_vector_type(8)))  short bf16x8;
typedef __attribute__((ext_vector_type(16))) float f32x16;

#define MFMA(A, B, C) __builtin_amdgcn_mfma_f32_32x32x16_bf16(A, B, C, 0, 0, 0)
#define AS_BF(v) (*(const bf16x8*)&(v))

__device__ inline unsigned int bfpack(float a, float b) {
    unsigned int ua = __float_as_uint(a), ub = __float_as_uint(b);
    unsigned int lo = (ua + 0x7FFFu + ((ua >> 16) & 1u)) >> 16;
    unsigned int hi = (ub + 0x7FFFu + ((ub >> 16) & 1u)) & 0xFFFF0000u;
    return hi | lo;
}
__device__ inline void split2pair(float a, float b, unsigned int& h, unsigned int& m) {
    h = bfpack(a, b);
    float ra = a - __uint_as_float(h << 16);
    float rb = b - __uint_as_float(h & 0xFFFF0000u);
    m = bfpack(ra, rb);
}

// w[e][k] f32 -> B-fragment order, 2-term bf16:
// byte = kt*16384 + j*4096 + term*2048 + kh*1024 + eq*512 + (e&31)*16
__global__ __launch_bounds__(256) void prep_kernel(const float* __restrict__ w,
                                                   unsigned int* __restrict__ wpack) {
    const int u = blockIdx.x * 256 + threadIdx.x;   // 0..16383
    const int e = u >> 8, k8 = u & 255;
    const float4 v0 = *(const float4*)(w + (size_t)e * DIM + k8 * 8);
    const float4 v1 = *(const float4*)(w + (size_t)e * DIM + k8 * 8 + 4);
    unsigned int h[4], m[4];
    split2pair(v0.x, v0.y, h[0], m[0]);
    split2pair(v0.z, v0.w, h[1], m[1]);
    split2pair(v1.x, v1.y, h[2], m[2]);
    split2pair(v1.z, v1.w, h[3], m[3]);
    const int kt = k8 >> 3, j = (k8 & 7) >> 1, kh = k8 & 1;
    const int eq = e >> 5, e5 = e & 31;
    char* base = (char*)wpack + (size_t)kt * 16384 + j * 4096 + kh * 1024 + eq * 512 + e5 * 16;
    *(uint4*)(base)        = (uint4){h[0], h[1], h[2], h[3]};
    *(uint4*)(base + 2048) = (uint4){m[0], m[1], m[2], m[3]};
}

__global__ __launch_bounds__(NT, 2) void router_kernel(
    const float* __restrict__ x,
    const unsigned int* __restrict__ wpack,
    const float* __restrict__ bias,
    float* __restrict__ out,     // [M*8] scores | [M*8] idx(f32) | [64] counts(f32)
    int* __restrict__ histws,    // [NBLK][64]
    int M)
{
    __shared__ __align__(16) char xs[2][8192];
    __shared__ int hist[NEXP];

    const int tid = threadIdx.x;
    const int bid = blockIdx.x;
    const int swz = (bid & 7) * (NBLK / 8) + (bid >> 3);   // bijective XCD swizzle
    const int row0 = swz * BM;
    if (tid < NEXP) hist[tid] = 0;

    // ---- stager: thread -> 2 granules (rows sr / sr+16), global linear, LDS XOR-swizzled
    const int sr = tid >> 4, sc = tid & 15;
    const float* xg0 = x + (size_t)(row0 + sr) * DIM + sc * 4;
    const float* xg1 = xg0 + (size_t)16 * DIM;
    const int o0 = sr * 256 + ((sc ^ (sr & 7)) << 4);

    // ---- compute roles: 4 waves = (expert-half eq) x (split-K s)
    const int wv = tid >> 6, lane = tid & 63;
    const int eq = wv & 1, s = wv >> 1;
    const int lr = lane & 31, kh = lane >> 5;
    const int rsw = lr & 7;
    const int c00 = (2 * s + 0) * 4 + kh * 2;
    const int c10 = (2 * s + 1) * 4 + kh * 2;
    const int ra00 = lr * 256 + (((c00 + 0) ^ rsw) << 4);
    const int ra01 = lr * 256 + (((c00 + 1) ^ rsw) << 4);
    const int ra10 = lr * 256 + (((c10 + 0) ^ rsw) << 4);
    const int ra11 = lr * 256 + (((c10 + 1) ^ rsw) << 4);
    const char* wgb = (const char*)wpack + (2 * s) * 4096 + kh * 1024 + eq * 512 + lr * 16;

    f32x16 acc = {};

    // named prefetch slots (rule #20: no runtime-indexed arrays)
    float4 xA0, xB0, xA1, xB1, xA2, xB2, xA3, xB3;
    uint4  wH0_0, wM0_0, wH1_0, wM1_0;
    uint4  wH0_1, wM0_1, wH1_1, wM1_1;

#define XLOAD(i, kt) do { xA##i = *(const float4*)(xg0 + (kt) * 64); \
                          xB##i = *(const float4*)(xg1 + (kt) * 64); } while (0)
#define WLOAD(i, kt) do { const char* wt_ = wgb + (size_t)(kt) * 16384; \
                          wH0_##i = *(const uint4*)(wt_); \
                          wM0_##i = *(const uint4*)(wt_ + 2048); \
                          wH1_##i = *(const uint4*)(wt_ + 4096); \
                          wM1_##i = *(const uint4*)(wt_ + 6144); } while (0)
#define XWRITE(i, par) do { char* b_ = &xs[par][0]; \
                            *(float4*)(b_ + o0)        = xA##i; \
                            *(float4*)(b_ + 4096 + o0) = xB##i; } while (0)
#define DOSPLIT(vlo, vhi, hv, mv) do { \
        unsigned int h_[4], m_[4]; \
        split2pair((vlo).x, (vlo).y, h_[0], m_[0]); \
        split2pair((vlo).z, (vlo).w, h_[1], m_[1]); \
        split2pair((vhi).x, (vhi).y, h_[2], m_[2]); \
        split2pair((vhi).z, (vhi).w, h_[3], m_[3]); \
        hv = (uint4){h_[0], h_[1], h_[2], h_[3]}; \
        mv = (uint4){m_[0], m_[1], m_[2], m_[3]}; \
    } while (0)
#define COMPUTE(i) do { \
        const char* buf_ = &xs[i][0]; \
        float4 a0_ = *(const float4*)(buf_ + ra00); \
        float4 a1_ = *(const float4*)(buf_ + ra01); \
        float4 a2_ = *(const float4*)(buf_ + ra10); \
        float4 a3_ = *(const float4*)(buf_ + ra11); \
        uint4 ah0_, am0_, ah1_, am1_; \
        DOSPLIT(a0_, a1_, ah0_, am0_); \
        DOSPLIT(a2_, a3_, ah1_, am1_); \
        acc = MFMA(AS_BF(ah0_), AS_BF(wH0_##i), acc); \
        acc = MFMA(AS_BF(am0_), AS_BF(wH0_##i), acc); \
        acc = MFMA(AS_BF(ah0_), AS_BF(wM0_##i), acc); \
        acc = MFMA(AS_BF(ah1_), AS_BF(wH1_##i), acc); \
        acc = MFMA(AS_BF(am1_), AS_BF(wH1_##i), acc); \
        acc = MFMA(AS_BF(ah1_), AS_BF(wM1_##i), acc); \
    } while (0)
#define SYNC do { asm volatile("s_waitcnt lgkmcnt(0)" ::: "memory"); \
                  __builtin_amdgcn_s_barrier(); } while (0)

    // prologue: tiles 0..3 in x slots, tiles 0..1 in w slots, tile 0 into LDS[0]
    XLOAD(0, 0); XLOAD(1, 1); XLOAD(2, 2); XLOAD(3, 3);
    WLOAD(0, 0); WLOAD(1, 1);
    XWRITE(0, 0);
    SYNC;

    for (int t4 = 0; t4 < KT; t4 += 4) {
        // tile t4+0: par0, wslot0, xslot0
        COMPUTE(0);
        XWRITE(1, 1);
        if (t4 + 4 < KT) XLOAD(0, t4 + 4);
        if (t4 + 2 < KT) WLOAD(0, t4 + 2);
        SYNC;
        // tile t4+1: par1, wslot1, xslot1
        COMPUTE(1);
        XWRITE(2, 0);
        if (t4 + 5 < KT) XLOAD(1, t4 + 5);
        if (t4 + 3 < KT) WLOAD(1, t4 + 3);
        SYNC;
        // tile t4+2: par0, wslot0, xslot2
        COMPUTE(0);
        XWRITE(3, 1);
        if (t4 + 6 < KT) XLOAD(2, t4 + 6);
        if (t4 + 4 < KT) WLOAD(0, t4 + 4);
        SYNC;
        // tile t4+3: par1, wslot1, xslot3
        COMPUTE(1);
        if (t4 + 4 < KT) XWRITE(0, 0);
        if (t4 + 7 < KT) XLOAD(3, t4 + 7);
        if (t4 + 5 < KT) WLOAD(1, t4 + 5);
        SYNC;
    }
#undef SYNC
#undef COMPUTE
#undef DOSPLIT
#undef XWRITE
#undef WLOAD
#undef XLOAD

    __syncthreads();

    // ---- split-K reduce + bias into lg[32][66] (aliases xs)
    float* lg = (float*)&xs[0][0];
    const float biasv = bias[eq * 32 + lr];
    if (s == 0) {
        #pragma unroll
        for (int r = 0; r < 16; ++r) {
            const int rr = (r & 3) + 8 * (r >> 2) + 4 * kh;   // verified C-layout
            lg[rr * 66 + eq * 32 + lr] = acc[r];
        }
    }
    __syncthreads();
    if (s == 1) {
        #pragma unroll
        for (int r = 0; r < 16; ++r) {
            const int rr = (r & 3) + 8 * (r >> 2) + 4 * kh;
            const int idx = rr * 66 + eq * 32 + lr;
            lg[idx] = lg[idx] + acc[r] + biasv;
        }
    }
    __syncthreads();

    // ---- top-k + softmax + histogram (verified epilogue); wave wv: rows wv*8..+8
    float* out_scores = out;
    float* out_idx    = out + (size_t)M * TOPK;

    for (int r8 = 0; r8 < 8; ++r8) {
        const int row = wv * 8 + r8;
        float vm = lg[row * 66 + lane];
        float vals[TOPK];
        int   ids[TOPK];
        #pragma unroll
        for (int k = 0; k < TOPK; ++k) {
            float mv = vm;
            int   mi = lane;
            #pragma unroll
            for (int off = 32; off > 0; off >>= 1) {
                float ov = __shfl_xor(mv, off);
                int   oi = __shfl_xor(mi, off);
                if (ov > mv || (ov == mv && oi < mi)) { mv = ov; mi = oi; }
            }
            vals[k] = mv; ids[k] = mi;
            if (lane == mi) { vm = -INFINITY; atomicAdd(&hist[mi], 1); }
        }
        if (lane == 0) {
            const float m = vals[0];
            float e[TOPK];
            float ssum = 0.f;
            #pragma unroll
            for (int k = 0; k < TOPK; ++k) { e[k] = expf(vals[k] - m); ssum += e[k]; }
            const float inv = 1.0f / ssum;
            const size_t base = (size_t)(row0 + row) * TOPK;
            #pragma unroll
            for (int k = 0; k < TOPK; ++k) {
                out_scores[base + k] = e[k] * inv;
                out_idx[base + k]    = (float)ids[k];
            }
        }
    }

    __syncthreads();
    if (tid < NEXP) histws[bid * NEXP + tid] = hist[tid];
}

__global__ __launch_bounds__(512) void reduce_kernel(const int* __restrict__ histws,
                                                     float* __restrict__ counts) {
    __shared__ int part[8][NEXP];
    const int t = threadIdx.x;
    const int e = t & 63, c = t >> 6;
    int sm = 0;
    for (int b = c; b < NBLK; b += 8) sm += histws[b * NEXP + e];
    part[c][e] = sm;
    __syncthreads();
    if (t < NEXP) {
        int tot = 0;
        #pragma unroll
        for (int i = 0; i < 8; ++i) tot += part[i][t];
        counts[t] = (float)tot;
    }
}

extern "C" void kernel_launch(void* const* d_in, const int* in_sizes, int n_in,
                              void* d_out, int out_size, void* d_ws, size_t ws_size,
                              hipStream_t stream) {
    const float* x    = (const float*)d_in[0];
    const float* w    = (const float*)d_in[1];
    const float* bias = (const float*)d_in[2];
    float* out = (float*)d_out;
    const int M = in_sizes[0] / DIM;   // 16384 rows

    unsigned int* wpack = (unsigned int*)d_ws;                      // 512 KB
    int* histws = (int*)((char*)d_ws + (size_t)NEXP * DIM * 4);     // 128 KB
    float* out_counts = out + (size_t)2 * M * TOPK;

    prep_kernel<<<64, 256, 0, stream>>>(w, wpack);
    router_kernel<<<NBLK, NT, 0, stream>>>(x, wpack, bias, out, histws, M);
    reduce_kernel<<<1, 512, 0, stream>>>(histws, out_counts);
}

// Round 9
// 68.107 us; speedup vs baseline: 2.8546x; 1.2627x over previous
//
#include <hip/hip_runtime.h>
#include <math.h>

#define DIM   2048
#define NEXP  64
#define TOPK  8
#define ROWS  32           // rows per block (all 8 waves share, split-K-8)
#define NT    512
#define NBLK  512          // M / ROWS
#define LROW  36           // padded LDS row stride (floats): 144 B = 9*16B

typedef __attribute__((ext_vector_type(8)))  short bf16x8;
typedef __attribute__((ext_vector_type(16))) float f32x16;

#define MFMA(A, B, C) __builtin_amdgcn_mfma_f32_32x32x16_bf16(A, B, C, 0, 0, 0)
#define AS_BF(v) (*(const bf16x8*)&(v))

__device__ inline unsigned int bfpack(float a, float b) {
    unsigned int ua = __float_as_uint(a), ub = __float_as_uint(b);
    unsigned int lo = (ua + 0x7FFFu + ((ua >> 16) & 1u)) >> 16;
    unsigned int hi = (ub + 0x7FFFu + ((ub >> 16) & 1u)) & 0xFFFF0000u;
    return hi | lo;
}
__device__ inline void split2pair(float a, float b, unsigned int& h, unsigned int& m) {
    h = bfpack(a, b);
    float ra = a - __uint_as_float(h << 16);
    float rb = b - __uint_as_float(h & 0xFFFF0000u);
    m = bfpack(ra, rb);
}

// w[e][k] f32 -> B-fragment stream per K-slice:
// byte = wv*65536 + t*8192 + (col*4 + ks*2 + term)*1024 + lane*16
//   lane = kh*32 + (e&31), col = e>>5, k = wv*256 + t*32 + ks*16 + kh*8 + j
__global__ __launch_bounds__(256) void prep_kernel(const float* __restrict__ w,
                                                   unsigned int* __restrict__ wpack) {
    const int u = blockIdx.x * 256 + threadIdx.x;   // 0..16383
    const int e = u >> 8, k8 = u & 255;
    const float4 v0 = *(const float4*)(w + (size_t)e * DIM + k8 * 8);
    const float4 v1 = *(const float4*)(w + (size_t)e * DIM + k8 * 8 + 4);
    unsigned int h[4], m[4];
    split2pair(v0.x, v0.y, h[0], m[0]);
    split2pair(v0.z, v0.w, h[1], m[1]);
    split2pair(v1.x, v1.y, h[2], m[2]);
    split2pair(v1.z, v1.w, h[3], m[3]);
    const int wv = k8 >> 5, t = (k8 >> 2) & 7, ks = (k8 >> 1) & 1, kh = k8 & 1;
    const int col = e >> 5, lane = kh * 32 + (e & 31);
    char* base = (char*)wpack + (size_t)wv * 65536 + t * 8192
               + (col * 4 + ks * 2) * 1024 + lane * 16;
    *(uint4*)(base)        = (uint4){h[0], h[1], h[2], h[3]};   // term h
    *(uint4*)(base + 1024) = (uint4){m[0], m[1], m[2], m[3]};   // term m
}

__global__ __launch_bounds__(NT, 4) void router_kernel(
    const float* __restrict__ x,
    const unsigned int* __restrict__ wpack,
    const float* __restrict__ bias,
    float* __restrict__ out,     // [M*8] scores | [M*8] idx(f32) | [64] counts(f32)
    int* __restrict__ histws,    // [NBLK][64]
    int M)
{
    __shared__ __align__(16) float xbuf[8][2][ROWS][LROW];   // 73728 B, wave-private [wv]
    __shared__ int hist[NEXP];

    const int tid  = threadIdx.x;
    const int bid  = blockIdx.x;
    const int swz  = (bid & 7) * (NBLK / 8) + (bid >> 3);    // bijective XCD swizzle
    const int row0 = swz * ROWS;
    if (tid < NEXP) hist[tid] = 0;

    const int wv   = tid >> 6;      // 0..7 : K-slice (split-K-8)
    const int lane = tid & 63;
    const int lr   = lane & 31;
    const int kh   = lane >> 5;
    const int la   = lane >> 3;     // 0..7  staging row-in-group
    const int lg8  = lane & 7;      // 0..7  staging granule

    // coalesced x sources: load i covers rows i*8..i*8+7, 128 B per row
    const float* xg0 = x + (size_t)(row0 +  0 + la) * DIM + wv * 256 + lg8 * 4;
    const float* xg1 = x + (size_t)(row0 +  8 + la) * DIM + wv * 256 + lg8 * 4;
    const float* xg2 = x + (size_t)(row0 + 16 + la) * DIM + wv * 256 + lg8 * 4;
    const float* xg3 = x + (size_t)(row0 + 24 + la) * DIM + wv * 256 + lg8 * 4;
    // w fragment stream (register-direct, coalesced 1 KB per frag-load)
    const char* wsl = (const char*)wpack + (size_t)wv * 65536 + lane * 16;
    // LDS write/read bases (wave-private)
    float* dsb0 = &xbuf[wv][0][la][lg8 * 4];
    float* crd  = &xbuf[wv][0][lr][0];

    f32x16 acc0 = {}, acc1 = {};
    float4 xq0[4], xq1[4];
    uint4  wf0[8], wf1[8];

#define XLOAD(d, t) do { \
        xq##d[0] = *(const float4*)(xg0 + (t) * 32); \
        xq##d[1] = *(const float4*)(xg1 + (t) * 32); \
        xq##d[2] = *(const float4*)(xg2 + (t) * 32); \
        xq##d[3] = *(const float4*)(xg3 + (t) * 32); } while (0)
#define WLOAD(d, t) do { const char* wt_ = wsl + (t) * 8192; \
        wf##d[0] = *(const uint4*)(wt_);          \
        wf##d[1] = *(const uint4*)(wt_ + 1024);   \
        wf##d[2] = *(const uint4*)(wt_ + 2048);   \
        wf##d[3] = *(const uint4*)(wt_ + 3072);   \
        wf##d[4] = *(const uint4*)(wt_ + 4096);   \
        wf##d[5] = *(const uint4*)(wt_ + 5120);   \
        wf##d[6] = *(const uint4*)(wt_ + 6144);   \
        wf##d[7] = *(const uint4*)(wt_ + 7168); } while (0)
#define DSWRITE(d, par) do { float* b_ = dsb0 + (par) * (ROWS * LROW); \
        *(float4*)(b_ +   0 * LROW) = xq##d[0]; \
        *(float4*)(b_ +   8 * LROW) = xq##d[1]; \
        *(float4*)(b_ +  16 * LROW) = xq##d[2]; \
        *(float4*)(b_ +  24 * LROW) = xq##d[3]; } while (0)
#define DOSPLIT(vlo, vhi, hv, mv) do { \
        unsigned int h_[4], m_[4]; \
        split2pair((vlo).x, (vlo).y, h_[0], m_[0]); \
        split2pair((vlo).z, (vlo).w, h_[1], m_[1]); \
        split2pair((vhi).x, (vhi).y, h_[2], m_[2]); \
        split2pair((vhi).z, (vhi).w, h_[3], m_[3]); \
        hv = (uint4){h_[0], h_[1], h_[2], h_[3]}; \
        mv = (uint4){m_[0], m_[1], m_[2], m_[3]}; \
    } while (0)
#define COMPUTE(d, par) do { const float* c_ = crd + (par) * (ROWS * LROW); \
        float4 a0lo_ = *(const float4*)(c_ + 0 * 16 + kh * 8); \
        float4 a0hi_ = *(const float4*)(c_ + 0 * 16 + kh * 8 + 4); \
        float4 a1lo_ = *(const float4*)(c_ + 1 * 16 + kh * 8); \
        float4 a1hi_ = *(const float4*)(c_ + 1 * 16 + kh * 8 + 4); \
        uint4 ah_, am_; \
        DOSPLIT(a0lo_, a0hi_, ah_, am_); \
        acc0 = MFMA(AS_BF(ah_), AS_BF(wf##d[0]), acc0); \
        acc0 = MFMA(AS_BF(am_), AS_BF(wf##d[0]), acc0); \
        acc0 = MFMA(AS_BF(ah_), AS_BF(wf##d[1]), acc0); \
        acc1 = MFMA(AS_BF(ah_), AS_BF(wf##d[4]), acc1); \
        acc1 = MFMA(AS_BF(am_), AS_BF(wf##d[4]), acc1); \
        acc1 = MFMA(AS_BF(ah_), AS_BF(wf##d[5]), acc1); \
        DOSPLIT(a1lo_, a1hi_, ah_, am_); \
        acc0 = MFMA(AS_BF(ah_), AS_BF(wf##d[2]), acc0); \
        acc0 = MFMA(AS_BF(am_), AS_BF(wf##d[2]), acc0); \
        acc0 = MFMA(AS_BF(ah_), AS_BF(wf##d[3]), acc0); \
        acc1 = MFMA(AS_BF(ah_), AS_BF(wf##d[6]), acc1); \
        acc1 = MFMA(AS_BF(am_), AS_BF(wf##d[6]), acc1); \
        acc1 = MFMA(AS_BF(ah_), AS_BF(wf##d[7]), acc1); \
    } while (0)

    // ---- barrier-free wave-private pipeline over 8 K32-tiles, depth-2 rings ----
    XLOAD(0, 0); WLOAD(0, 0); XLOAD(1, 1); WLOAD(1, 1);
    DSWRITE(0, 0);
    /*t=0*/ XLOAD(0, 2); DSWRITE(1, 1); COMPUTE(0, 0); WLOAD(0, 2);
    /*t=1*/ XLOAD(1, 3); DSWRITE(0, 0); COMPUTE(1, 1); WLOAD(1, 3);
    /*t=2*/ XLOAD(0, 4); DSWRITE(1, 1); COMPUTE(0, 0); WLOAD(0, 4);
    /*t=3*/ XLOAD(1, 5); DSWRITE(0, 0); COMPUTE(1, 1); WLOAD(1, 5);
    /*t=4*/ XLOAD(0, 6); DSWRITE(1, 1); COMPUTE(0, 0); WLOAD(0, 6);
    /*t=5*/ XLOAD(1, 7); DSWRITE(0, 0); COMPUTE(1, 1); WLOAD(1, 7);
    /*t=6*/             DSWRITE(1, 1); COMPUTE(0, 0);
    /*t=7*/                            COMPUTE(1, 1);
#undef COMPUTE
#undef DOSPLIT
#undef DSWRITE
#undef WLOAD
#undef XLOAD

    __syncthreads();

    // ---- split-K partials into lg[8][32][66] (aliases xbuf) ----
    float* lgf = (float*)xbuf;
    #pragma unroll
    for (int r = 0; r < 16; ++r) {
        const int rr = (r & 3) + 8 * (r >> 2) + 4 * kh;   // verified C-layout (m74/m101)
        lgf[(wv * 32 + rr) * 66 + lr]      = acc0[r];
        lgf[(wv * 32 + rr) * 66 + 32 + lr] = acc1[r];
    }
    __syncthreads();

    // ---- top-k + softmax + histogram (verified epilogue); wave wv: 4 rows ----
    float* out_scores = out;
    float* out_idx    = out + (size_t)M * TOPK;

    #pragma unroll
    for (int i = 0; i < 4; ++i) {
        const int row = wv * 4 + i;
        float vm = bias[lane];
        #pragma unroll
        for (int p = 0; p < 8; ++p) vm += lgf[(p * 32 + row) * 66 + lane];

        float vals[TOPK];
        int   ids[TOPK];
        #pragma unroll
        for (int k = 0; k < TOPK; ++k) {
            float mv = vm;
            int   mi = lane;
            #pragma unroll
            for (int off = 32; off > 0; off >>= 1) {
                float ov = __shfl_xor(mv, off);
                int   oi = __shfl_xor(mi, off);
                if (ov > mv || (ov == mv && oi < mi)) { mv = ov; mi = oi; }
            }
            vals[k] = mv; ids[k] = mi;
            if (lane == mi) { vm = -INFINITY; atomicAdd(&hist[mi], 1); }
        }
        if (lane == 0) {
            const float m = vals[0];
            float e[TOPK];
            float ssum = 0.f;
            #pragma unroll
            for (int k = 0; k < TOPK; ++k) { e[k] = expf(vals[k] - m); ssum += e[k]; }
            const float inv = 1.0f / ssum;
            const size_t base = (size_t)(row0 + row) * TOPK;
            #pragma unroll
            for (int k = 0; k < TOPK; ++k) {
                out_scores[base + k] = e[k] * inv;
                out_idx[base + k]    = (float)ids[k];
            }
        }
    }

    __syncthreads();
    if (tid < NEXP) histws[bid * NEXP + tid] = hist[tid];
}

__global__ __launch_bounds__(512) void reduce_kernel(const int* __restrict__ histws,
                                                     float* __restrict__ counts) {
    __shared__ int part[8][NEXP];
    const int t = threadIdx.x;
    const int e = t & 63, c = t >> 6;
    int sm = 0;
    for (int b = c; b < NBLK; b += 8) sm += histws[b * NEXP + e];
    part[c][e] = sm;
    __syncthreads();
    if (t < NEXP) {
        int tot = 0;
        #pragma unroll
        for (int i = 0; i < 8; ++i) tot += part[i][t];
        counts[t] = (float)tot;
    }
}

extern "C" void kernel_launch(void* const* d_in, const int* in_sizes, int n_in,
                              void* d_out, int out_size, void* d_ws, size_t ws_size,
                              hipStream_t stream) {
    const float* x    = (const float*)d_in[0];
    const float* w    = (const float*)d_in[1];
    const float* bias = (const float*)d_in[2];
    float* out = (float*)d_out;
    const int M = in_sizes[0] / DIM;   // 16384 rows

    unsigned int* wpack = (unsigned int*)d_ws;                      // 512 KB
    int* histws = (int*)((char*)d_ws + (size_t)NEXP * DIM * 4);     // 128 KB
    float* out_counts = out + (size_t)2 * M * TOPK;

    prep_kernel<<<64, 256, 0, stream>>>(w, wpack);
    router_kernel<<<NBLK, NT, 0, stream>>>(x, wpack, bias, out, histws, M);
    reduce_kernel<<<1, 512, 0, stream>>>(histws, out_counts);
}